// Round 6
// baseline (16274.591 us; speedup 1.0000x reference)
//
#include <hip/hip_runtime.h>

// Problem constants
#define BB   32      // batch
#define TT_  512     // sequence length
#define DD   1024    // input dim
#define HH   1024    // hidden
#define RR_  64      // low-rank
#define FH   4096    // 4*H
#define TC   32      // timestep chunk
#define NC   16      // number of chunks
#define NW   33      // worker blocks per fused step

typedef __attribute__((ext_vector_type(8))) short          bf16x8;   // MFMA A/B frag
typedef __attribute__((ext_vector_type(4))) float          f32x4;    // MFMA C/D frag
typedef __attribute__((ext_vector_type(4))) unsigned short us4;

// fp32 -> bf16 bits, round-to-nearest-even
__device__ __forceinline__ unsigned short f2bf(float x) {
    union { float f; unsigned u; } v; v.f = x;
    return (unsigned short)((v.u + 0x7FFFu + ((v.u >> 16) & 1u)) >> 16);
}
__device__ __forceinline__ float bf2f(unsigned short u) {
    union { unsigned u32; float f; } v; v.u32 = ((unsigned)u) << 16; return v.f;
}

// ---------------------------------------------------------------------------
// Zero-init (ws poisoned 0xAA before every call)
// ---------------------------------------------------------------------------
__global__ void init_zero(float4* p, int n4) {
    int i = blockIdx.x * blockDim.x + threadIdx.x;
    if (i < n4) p[i] = make_float4(0.f, 0.f, 0.f, 0.f);
}

// fp32 -> bf16 bulk convert (U matrices / Bm, once per call)
__global__ void cvt_bf16(const float* __restrict__ src,
                         unsigned short* __restrict__ dst, int n4) {
    int i = blockIdx.x * blockDim.x + threadIdx.x;
    int stride = gridDim.x * blockDim.x;
    for (; i < n4; i += stride) {
        float4 v = ((const float4*)src)[i];
        us4 t; t.x = f2bf(v.x); t.y = f2bf(v.y); t.z = f2bf(v.z); t.w = f2bf(v.w);
        ((us4*)dst)[i] = t;
    }
}

// ---------------------------------------------------------------------------
// GEMM tile body (round-4 proven structure): fp32 in, bf16 RNE at LDS staging,
// fp32 accum; output transposed C[((m>>5)*N + n)*32 + (m&31)], bf16 or fp32.
// BM=64, BK=32; BN=128 (MI=2,NI=4) or BN=64 (MI=2,NI=2). 256 threads, 2x2 waves.
// smem need: (BM+BN)*BK ushorts = 12 KB (BN=128).
// ---------------------------------------------------------------------------
template<int BN, bool OUTBF>
__device__ __forceinline__ void gemm_body(
    int bxx, int byy,
    const float* __restrict__ Abase, long strideT, long strideB,
    const float* __restrict__ W, const float* __restrict__ bias,
    void* __restrict__ Cout, int N, int K, char* smem)
{
    constexpr int BM  = 64, BK = 32;
    constexpr int WTM = BM / 2, WTN = BN / 2;
    constexpr int MI  = WTM / 16, NI = WTN / 16;
    constexpr int AU  = BM * (BK / 4) / 256;   // 2
    constexpr int BU  = BN * (BK / 4) / 256;   // 4 or 2

    unsigned short* As = (unsigned short*)smem;           // [BM][BK]
    unsigned short* Bs = As + BM * BK;                    // [BN][BK]

    const int tid  = threadIdx.x;
    const int lane = tid & 63, wave = tid >> 6;
    const int wm   = wave >> 1, wn = wave & 1;
    const int kg   = lane >> 4;
    const int lr   = lane & 15;
    const long bm  = (long)byy * BM;
    const long bn  = (long)bxx * BN;

    const float* ag[AU]; int alds[AU];
    const float* bg[BU]; int blds[BU];
#pragma unroll
    for (int i = 0; i < AU; ++i) {
        int u = i * 256 + tid, row = u >> 3, uc = u & 7;
        long m = bm + row;
        ag[i]   = Abase + (m >> 5) * strideT + (m & 31) * strideB + uc * 4;
        alds[i] = row * BK + uc * 4;
    }
#pragma unroll
    for (int i = 0; i < BU; ++i) {
        int u = i * 256 + tid, row = u >> 3, uc = u & 7;
        bg[i]   = W + (long)(bn + row) * K + uc * 4;
        blds[i] = row * BK + uc * 4;
    }

    f32x4 acc[MI][NI] = {};

    float4 av[AU], bv[BU];
#pragma unroll
    for (int i = 0; i < AU; ++i) av[i] = *(const float4*)(ag[i]);
#pragma unroll
    for (int i = 0; i < BU; ++i) bv[i] = *(const float4*)(bg[i]);

    for (int k0 = 0; k0 < K; k0 += BK) {
        __syncthreads();
#pragma unroll
        for (int i = 0; i < AU; ++i) {
            us4 t; t.x = f2bf(av[i].x); t.y = f2bf(av[i].y);
                   t.z = f2bf(av[i].z); t.w = f2bf(av[i].w);
            *(us4*)&As[alds[i]] = t;
        }
#pragma unroll
        for (int i = 0; i < BU; ++i) {
            us4 t; t.x = f2bf(bv[i].x); t.y = f2bf(bv[i].y);
                   t.z = f2bf(bv[i].z); t.w = f2bf(bv[i].w);
            *(us4*)&Bs[blds[i]] = t;
        }
        __syncthreads();

        if (k0 + BK < K) {
#pragma unroll
            for (int i = 0; i < AU; ++i) av[i] = *(const float4*)(ag[i] + k0 + BK);
#pragma unroll
            for (int i = 0; i < BU; ++i) bv[i] = *(const float4*)(bg[i] + k0 + BK);
        }

        bf16x8 af[MI], bfr[NI];
#pragma unroll
        for (int mi = 0; mi < MI; ++mi)
            af[mi] = *(const bf16x8*)&As[(wm * WTM + mi * 16 + lr) * BK + kg * 8];
#pragma unroll
        for (int ni = 0; ni < NI; ++ni)
            bfr[ni] = *(const bf16x8*)&Bs[(wn * WTN + ni * 16 + lr) * BK + kg * 8];
#pragma unroll
        for (int mi = 0; mi < MI; ++mi)
#pragma unroll
            for (int ni = 0; ni < NI; ++ni)
                acc[mi][ni] = __builtin_amdgcn_mfma_f32_16x16x32_bf16(
                    af[mi], bfr[ni], acc[mi][ni], 0, 0, 0);
    }

    const int rbase = (lane >> 4) * 4;
#pragma unroll
    for (int mi = 0; mi < MI; ++mi) {
        long m0 = bm + wm * WTM + mi * 16 + rbase;
        long trow = m0 >> 5; int bq = (int)(m0 & 31);
#pragma unroll
        for (int ni = 0; ni < NI; ++ni) {
            long n = bn + wn * WTN + ni * 16 + lr;
            float bia = bias ? bias[n] : 0.f;
            if (OUTBF) {
                us4 t; t.x = f2bf(acc[mi][ni][0] + bia);
                       t.y = f2bf(acc[mi][ni][1] + bia);
                       t.z = f2bf(acc[mi][ni][2] + bia);
                       t.w = f2bf(acc[mi][ni][3] + bia);
                *(us4*)&((unsigned short*)Cout)[(trow * N + n) * 32 + bq] = t;
            } else {
                float4 v = make_float4(acc[mi][ni][0] + bia, acc[mi][ni][1] + bia,
                                       acc[mi][ni][2] + bia, acc[mi][ni][3] + bia);
                *(float4*)&((float*)Cout)[(trow * N + n) * 32 + bq] = v;
            }
        }
    }
}

// standalone wrapper for the prologue (chunk-0 xw projection)
__global__ __launch_bounds__(256) void gemm_pro(
    const float* __restrict__ Abase, long strideT, long strideB,
    const float* __restrict__ W, const float* __restrict__ bias,
    unsigned short* __restrict__ C, int N, int K)
{
    __shared__ __align__(16) char smem[12288];
    gemm_body<128, true>(blockIdx.x, blockIdx.y, Abase, strideT, strideB,
                         W, bias, C, N, K, smem);
}

// ---------------------------------------------------------------------------
// Scan-step bodies (round-4 math; xw now bf16). smem: [0,64K) h swizzled;
// [64K,72K) zsl[4][16][32]; [72K,80K) ssl[64][32] (mLSTM only).
// ---------------------------------------------------------------------------
__device__ __forceinline__ void slstm_body(
    int bx, const unsigned short* __restrict__ xwT,
    const unsigned short* __restrict__ Ubf, const float* __restrict__ bU,
    const float* __restrict__ alpha, const unsigned short* __restrict__ hin,
    unsigned short* __restrict__ hout, float* __restrict__ cst,
    float* __restrict__ out1t, char* smem)
{
    float* zsl = (float*)(smem + 65536);
    const int tid  = threadIdx.x;
    const int lane = tid & 63, wv = tid >> 6;
    const int j0   = bx * 16;
    const int lr   = lane & 15;
    const int koff = (lane >> 4) << 3;

    const uint4* hg = (const uint4*)hin;
#pragma unroll
    for (int i = 0; i < 16; ++i) {
        int u = tid + (i << 8);
        int o = u << 4;
        int sw = o ^ (((o >> 11) & 7) << 4);
        *(uint4*)(smem + sw) = hg[u];
    }
    __syncthreads();

    const unsigned short* Arow = Ubf + (((long)(wv * HH + j0 + lr)) << 10) + koff;
    const int base0 = lr * 2048 + koff * 2;
    const int base1 = (lr + 16) * 2048 + koff * 2;
    const int swz   = (lr & 7) << 4;

    f32x4 accZ0 = {0.f, 0.f, 0.f, 0.f}, accZ1 = {0.f, 0.f, 0.f, 0.f};
#pragma unroll 4
    for (int k0 = 0; k0 < 1024; k0 += 32) {
        bf16x8 a  = *(const bf16x8*)(Arow + k0);
        bf16x8 b0 = *(const bf16x8*)(smem + ((base0 + k0 * 2) ^ swz));
        bf16x8 b1 = *(const bf16x8*)(smem + ((base1 + k0 * 2) ^ swz));
        accZ0 = __builtin_amdgcn_mfma_f32_16x16x32_bf16(a, b0, accZ0, 0, 0, 0);
        accZ1 = __builtin_amdgcn_mfma_f32_16x16x32_bf16(a, b1, accZ1, 0, 0, 0);
    }
#pragma unroll
    for (int r = 0; r < 4; ++r) {
        int jj = ((lane >> 4) << 2) + r;
        zsl[wv * 512 + jj * 32 + lr]      = accZ0[r];
        zsl[wv * 512 + jj * 32 + lr + 16] = accZ1[r];
    }
    __syncthreads();

#pragma unroll
    for (int rep = 0; rep < 2; ++rep) {
        int p = (rep << 8) + tid;
        int j = p >> 5, b = p & 31;
        int n0 = j0 + j;
        float zi = bf2f(xwT[(long)n0 * 32 + b])            + zsl[j * 32 + b]        + bU[n0];
        float zf = bf2f(xwT[(long)(HH + n0) * 32 + b])     + zsl[512 + j * 32 + b]  + bU[HH + n0];
        float zo = bf2f(xwT[(long)(2 * HH + n0) * 32 + b]) + zsl[1024 + j * 32 + b] + bU[2 * HH + n0];
        float zg = bf2f(xwT[(long)(3 * HH + n0) * 32 + b]) + zsl[1536 + j * 32 + b] + bU[3 * HH + n0];
        float ig = 1.f / (1.f + expf(-zi));
        float fg = 1.f / (1.f + expf(-zf));
        float og = 1.f / (1.f + expf(-zo));
        float g  = tanhf(zg);
        float cold = cst[(long)b * HH + n0];
        float cn = alpha[n0] * (fg * cold + ig * g);
        float hn = og * tanhf(cn);
        cst[(long)b * HH + n0]  = cn;
        hout[(long)b * HH + n0] = f2bf(hn);
        out1t[(long)b * HH + n0] = hn;
    }
}

__device__ __forceinline__ void mlstm_body(
    int bx, const unsigned short* __restrict__ xwT,
    const unsigned short* __restrict__ Ubf, const float* __restrict__ bU,
    const float* __restrict__ Pmat, const unsigned short* __restrict__ Bmbf,
    const float* __restrict__ xaT, const unsigned short* __restrict__ hin,
    unsigned short* __restrict__ hout, float* __restrict__ cst,
    float* __restrict__ out, int t, char* smem)
{
    float* zsl = (float*)(smem + 65536);
    float* ssl = (float*)(smem + 65536 + 8192);
    const int tid  = threadIdx.x;
    const int lane = tid & 63, wv = tid >> 6;
    const int j0   = bx * 16;
    const int lr   = lane & 15;
    const int koff = (lane >> 4) << 3;

    const uint4* hg = (const uint4*)hin;
#pragma unroll
    for (int i = 0; i < 16; ++i) {
        int u = tid + (i << 8);
        int o = u << 4;
        int sw = o ^ (((o >> 11) & 7) << 4);
        *(uint4*)(smem + sw) = hg[u];
    }
    __syncthreads();

    const unsigned short* Arow = Ubf + (((long)(wv * HH + j0 + lr)) << 10) + koff;
    const unsigned short* Brow = Bmbf + (((long)(wv * 16 + lr)) << 10) + koff;
    const int base0 = lr * 2048 + koff * 2;
    const int base1 = (lr + 16) * 2048 + koff * 2;
    const int swz   = (lr & 7) << 4;

    f32x4 accZ0 = {0.f, 0.f, 0.f, 0.f}, accZ1 = {0.f, 0.f, 0.f, 0.f};
    f32x4 accS0 = {0.f, 0.f, 0.f, 0.f}, accS1 = {0.f, 0.f, 0.f, 0.f};
#pragma unroll 4
    for (int k0 = 0; k0 < 1024; k0 += 32) {
        bf16x8 a  = *(const bf16x8*)(Arow + k0);
        bf16x8 s  = *(const bf16x8*)(Brow + k0);
        bf16x8 b0 = *(const bf16x8*)(smem + ((base0 + k0 * 2) ^ swz));
        bf16x8 b1 = *(const bf16x8*)(smem + ((base1 + k0 * 2) ^ swz));
        accZ0 = __builtin_amdgcn_mfma_f32_16x16x32_bf16(a, b0, accZ0, 0, 0, 0);
        accZ1 = __builtin_amdgcn_mfma_f32_16x16x32_bf16(a, b1, accZ1, 0, 0, 0);
        accS0 = __builtin_amdgcn_mfma_f32_16x16x32_bf16(s, b0, accS0, 0, 0, 0);
        accS1 = __builtin_amdgcn_mfma_f32_16x16x32_bf16(s, b1, accS1, 0, 0, 0);
    }
#pragma unroll
    for (int r = 0; r < 4; ++r) {
        int jj = ((lane >> 4) << 2) + r;
        zsl[wv * 512 + jj * 32 + lr]      = accZ0[r];
        zsl[wv * 512 + jj * 32 + lr + 16] = accZ1[r];
        ssl[(wv * 16 + jj) * 32 + lr]      = accS0[r];
        ssl[(wv * 16 + jj) * 32 + lr + 16] = accS1[r];
    }
    __syncthreads();

#pragma unroll
    for (int i = 0; i < 8; ++i) {
        int idx = tid + (i << 8);
        ssl[idx] *= xaT[idx];
    }
    __syncthreads();

#pragma unroll
    for (int rep = 0; rep < 2; ++rep) {
        int p = (rep << 8) + tid;
        int j = p >> 5, b = p & 31;
        int n0 = j0 + j;
        float zi = bf2f(xwT[(long)n0 * 32 + b])            + zsl[j * 32 + b]        + bU[n0];
        float zf = bf2f(xwT[(long)(HH + n0) * 32 + b])     + zsl[512 + j * 32 + b]  + bU[HH + n0];
        float zo = bf2f(xwT[(long)(2 * HH + n0) * 32 + b]) + zsl[1024 + j * 32 + b] + bU[2 * HH + n0];
        float zg = bf2f(xwT[(long)(3 * HH + n0) * 32 + b]) + zsl[1536 + j * 32 + b] + bU[3 * HH + n0];
        float ig = 1.f / (1.f + expf(-zi));
        float fg = 1.f / (1.f + expf(-zf));
        float og = 1.f / (1.f + expf(-zo));
        float g  = tanhf(zg);
        const float* Pj = Pmat + (long)n0 * 64;
        float mx = 0.f;
#pragma unroll
        for (int r = 0; r < 64; ++r) mx += Pj[r] * ssl[r * 32 + b];
        float cold = cst[(long)b * HH + n0];
        float cn = fg * cold + ig * g + 0.1f * mx;
        float hn = og * tanhf(cn);
        cst[(long)b * HH + n0]  = cn;
        hout[(long)b * HH + n0] = f2bf(hn);
        out[(long)b * (TT_ * HH) + (long)t * HH + n0] = hn;
    }
}

// ---------------------------------------------------------------------------
// Fused step: blocks 0-63 sLSTM(ch p, step tt); 64-127 mLSTM(ch p-1, step tt);
// 128-160 GEMM workers computing projection tiles for the pipeline:
//   - Wm/A tiles of timestep-pair (tt/2 - 1) of chunk p (ready via kernel
//     boundary); steps 0,1 handle pair 15 of chunk p-1 (spill).
//   - xw-projection tiles of chunk p+1 fill the remaining worker slots.
// ---------------------------------------------------------------------------
__global__ __launch_bounds__(256) void fused_step(
    // sLSTM
    const unsigned short* xwTs_r, const unsigned short* UbfS,
    const float* bUs, const float* alpha,
    const unsigned short* hsin, unsigned short* hsout, float* cS, float* out1t,
    // mLSTM
    const unsigned short* xwTm_r, const unsigned short* UbfM, const float* bUm,
    const float* Pmat, const unsigned short* Bmbf, const float* xaT_r,
    const unsigned short* hmin, unsigned short* hmout, float* cM,
    float* out, int t,
    // workers
    const float* xnext, const float* Ws, const float* bWs,
    const float* Wm, const float* bWm, const float* Amat,
    const float* out1c,
    unsigned short* xwTs_w, unsigned short* xwTm_wc, unsigned short* xwTm_wp,
    float* xaT_wc, float* xaT_wp,
    int tt, int do_s, int do_m, int wm_cur_ok, int wm_prev_ok, int xw_ok)
{
    __shared__ __align__(16) char smem[81920];  // 80 KB
    const int bx = blockIdx.x;
    if (bx < 64) {
        if (do_s)
            slstm_body(bx, xwTs_r, UbfS, bUs, alpha, hsin, hsout, cS, out1t, smem);
    } else if (bx < 128) {
        if (do_m)
            mlstm_body(bx - 64, xwTm_r, UbfM, bUm, Pmat, Bmbf, xaT_r,
                       hmin, hmout, cM, out, t, smem);
    } else {
        const int w = bx - 128;
        const int even = !(tt & 1);
        const int nWm = even ? 17 : 16;
        if (w < nWm) {
            // Wm / A projection tile
            const int q = even ? w : 17 + w;          // 0..32
            const int prevband = (tt < 2);
            const int pair = prevband ? 15 : ((tt >> 1) - 1);
            const int ok = prevband ? wm_prev_ok : wm_cur_ok;
            if (ok) {
                unsigned short* xwTm_t = prevband ? xwTm_wp : xwTm_wc;
                float* xaT_t           = prevband ? xaT_wp : xaT_wc;
                if (q < 32)
                    gemm_body<128, true>(q, pair, out1c, (long)BB * HH, (long)HH,
                                         Wm, bWm, xwTm_t, FH, HH, smem);
                else
                    gemm_body<64, false>(0, pair, out1c, (long)BB * HH, (long)HH,
                                         Amat, nullptr, xaT_t, RR_, HH, smem);
            }
        } else {
            // xw projection tile for chunk p+1
            const int done = 33 * (tt >> 1) + ((tt & 1) ? 16 : 0);
            const int k = done + (w - nWm);
            if (k < 512 && xw_ok)
                gemm_body<128, true>(k & 31, k >> 5, xnext, (long)DD,
                                     (long)TT_ * DD, Ws, bWs, xwTs_w, FH, DD, smem);
        }
    }
}

// ---------------------------------------------------------------------------
// Launch. ~56 MB workspace. 549 launches total (5 prologue + 544 fused).
// ---------------------------------------------------------------------------
extern "C" void kernel_launch(void* const* d_in, const int* in_sizes, int n_in,
                              void* d_out, int out_size, void* d_ws, size_t ws_size,
                              hipStream_t stream) {
    const float* x     = (const float*)d_in[0];
    const float* Ws    = (const float*)d_in[1];
    const float* bWs   = (const float*)d_in[2];
    const float* Us    = (const float*)d_in[3];
    const float* bUs   = (const float*)d_in[4];
    const float* alpha = (const float*)d_in[5];
    const float* Wm    = (const float*)d_in[6];
    const float* bWm   = (const float*)d_in[7];
    const float* Um    = (const float*)d_in[8];
    const float* bUm   = (const float*)d_in[9];
    const float* A     = (const float*)d_in[10];
    const float* Bm    = (const float*)d_in[11];
    const float* P     = (const float*)d_in[12];
    float* out = (float*)d_out;

    // bf16 region
    unsigned short* xwTs0 = (unsigned short*)d_ws;            // TC*FH*32 sh (8 MB)
    unsigned short* xwTs1 = xwTs0 + (long)TC * FH * 32;
    unsigned short* xwTm0 = xwTs1 + (long)TC * FH * 32;
    unsigned short* xwTm1 = xwTm0 + (long)TC * FH * 32;
    unsigned short* UbfS  = xwTm1 + (long)TC * FH * 32;       // FH*HH sh (8 MB)
    unsigned short* UbfM  = UbfS + (long)FH * HH;
    unsigned short* Bmbf  = UbfM + (long)FH * HH;             // RR*HH sh (128 KB)
    // fp32 region
    float* out1c = (float*)(Bmbf + (long)RR_ * HH);           // TC*BB*HH f (4 MB)
    float* xaT0  = out1c + (long)TC * BB * HH;                // TC*RR*32 f (256 KB)
    float* xaT1  = xaT0 + (long)TC * RR_ * 32;
    // zeroed state region: 4 h bufs bf16 + 2 c bufs fp32 = 512 KB
    unsigned short* hbsA = (unsigned short*)(xaT1 + (long)TC * RR_ * 32);
    unsigned short* hbsB = hbsA + BB * HH;
    unsigned short* hbmA = hbsB + BB * HH;
    unsigned short* hbmB = hbmA + BB * HH;
    float* cS = (float*)(hbmB + BB * HH);
    float* cM = cS + BB * HH;

    init_zero<<<128, 256, 0, stream>>>((float4*)hbsA, 32768);

    cvt_bf16<<<2048, 256, 0, stream>>>(Us, UbfS, FH * HH / 4);
    cvt_bf16<<<2048, 256, 0, stream>>>(Um, UbfM, FH * HH / 4);
    cvt_bf16<<<64,   256, 0, stream>>>(Bm, Bmbf, RR_ * HH / 4);

    // prologue: xw projection of chunk 0
    gemm_pro<<<dim3(32, 16), 256, 0, stream>>>(
        x, (long)DD, (long)TT_ * DD, Ws, bWs, xwTs0, FH, DD);

    unsigned short* xwTsBuf[2] = {xwTs0, xwTs1};
    unsigned short* xwTmBuf[2] = {xwTm0, xwTm1};
    float* xaTBuf[2] = {xaT0, xaT1};

    for (int p = 0; p <= NC; ++p) {
        const int do_s = (p < NC), do_m = (p > 0);
        const int wm_cur_ok  = (p < NC);
        const int wm_prev_ok = (p > 0);
        const int xw_ok      = (p + 1 < NC);
        const float* xnext = x + (long)(p + 1) * TC * DD;   // deref'd only if xw_ok
        unsigned short* xwTs_r = xwTsBuf[p & 1];
        unsigned short* xwTs_w = xwTsBuf[(p + 1) & 1];
        unsigned short* xwTm_r = xwTmBuf[(p + 1) & 1];      // = (p-1)&1
        unsigned short* xwTm_wc = xwTmBuf[p & 1];
        float* xaT_r  = xaTBuf[(p + 1) & 1];
        float* xaT_wc = xaTBuf[p & 1];

        for (int tt = 0; tt < TC; ++tt) {
            const unsigned short* hsin = (tt & 1) ? hbsB : hbsA;
            unsigned short* hsout      = (tt & 1) ? hbsA : hbsB;
            const unsigned short* hmin = (tt & 1) ? hbmB : hbmA;
            unsigned short* hmout      = (tt & 1) ? hbmA : hbmB;
            fused_step<<<128 + NW, 256, 0, stream>>>(
                xwTs_r + (long)tt * FH * 32, UbfS, bUs, alpha,
                hsin, hsout, cS, out1c + (long)tt * BB * HH,
                xwTm_r + (long)tt * FH * 32, UbfM, bUm, P, Bmbf,
                xaT_r + (long)tt * RR_ * 32,
                hmin, hmout, cM, out, (p - 1) * TC + tt,
                xnext, Ws, bWs, Wm, bWm, A, out1c,
                xwTs_w, xwTm_wc, xwTm_r, xaT_wc, xaT_r,
                tt, do_s, do_m, wm_cur_ok, wm_prev_ok, xw_ok);
        }
    }
}